// Round 1
// baseline (3545.346 us; speedup 1.0000x reference)
//
#include <hip/hip_runtime.h>

// Residual VQ: N=65536 points, D=128, S=4 stages, K=2048 codewords.
// Outputs (flat, float32): x_q [N*D] @0, mean_loss @N*D, indices [N,S] as float @N*D+1.
//
// Strategy: stages are sequential per-point only -> one fused kernel.
// Per block: 64 points resident in LDS (Rt). Per stage: stream codebook
// through LDS in 64-codeword chunks (two 64-wide D-halves), each thread
// computes a 4x4 (point x codeword) dot tile, argmin via strict < (k
// ascending) + tie-broken shuffle reduce, then cooperative residual
// update (exact c - r, also yields the loss term). x_q = x - residual.

#define NPTS_TOTAL 65536
#define DDIM       128
#define NSTAGE     4
#define KCB        2048
#define BETA_F     0.25f

#define TPB    256
#define PTS    64          // points per block
#define CHUNK  64          // codewords per LDS chunk
#define NCHUNK (KCB / CHUNK)
#define LDR_R  132         // padded row stride (floats) for residual tile
#define LDR_C  68          // padded row stride for codeword half-chunk

#define WS_LOSS  0         // 4 floats
#define WS_CNORM 16        // NSTAGE*KCB floats

#define XQ_SIZE  (NPTS_TOTAL * DDIM)
#define IDX_OFF  (XQ_SIZE + 1)

__global__ void cnorm_init(const float* __restrict__ cb, float* __restrict__ ws) {
    int t = blockIdx.x * blockDim.x + threadIdx.x;   // 131072 threads
    int row = t >> 4;                                // 0..8191  (s*K + k)
    int q   = t & 15;
    const float4* rp = (const float4*)(cb + (size_t)row * DDIM);
    float s = 0.f;
    #pragma unroll
    for (int j = 0; j < 2; ++j) {
        float4 v = rp[q * 2 + j];
        s += v.x * v.x + v.y * v.y + v.z * v.z + v.w * v.w;
    }
    #pragma unroll
    for (int m = 1; m < 16; m <<= 1) s += __shfl_xor(s, m);
    if (q == 0) ws[WS_CNORM + row] = s;
    if (t < 4) ws[WS_LOSS + t] = 0.f;                // zero loss accumulators
}

__global__ __launch_bounds__(TPB, 3)
void rvq_main(const float* __restrict__ x, const float* __restrict__ cb,
              float* __restrict__ out, float* __restrict__ ws) {
    __shared__ float Rt[PTS][LDR_R];     // residual tile, full D
    __shared__ float Ct[CHUNK][LDR_C];   // codeword half-chunk (64 d's)
    __shared__ float sCn[CHUNK];
    __shared__ int   sIdx[PTS];

    const int t  = threadIdx.x;
    const int tc = t & 15;               // codeword-group lane (4 cw each)
    const int tp = t >> 4;               // point-group lane (4 pts each)
    const size_t n0 = (size_t)blockIdx.x * PTS;
    const float4* xblk = (const float4*)(x + n0 * DDIM);

    // load x tile -> Rt (coalesced float4)
    #pragma unroll
    for (int j = 0; j < 8; ++j) {
        int f4 = t + j * TPB;            // 0..2047
        int p  = f4 >> 5;                // 32 float4 per row
        int d4 = f4 & 31;
        float4 v = xblk[f4];
        *(float4*)&Rt[p][d4 * 4] = v;
    }

    float lossAcc[NSTAGE];
    #pragma unroll
    for (int s = 0; s < NSTAGE; ++s) lossAcc[s] = 0.f;

    const float4* rp[4];
    #pragma unroll
    for (int i = 0; i < 4; ++i) rp[i] = (const float4*)&Rt[tp * 4 + i][0];
    const float4* cp[4];
    #pragma unroll
    for (int j = 0; j < 4; ++j) cp[j] = (const float4*)&Ct[tc * 4 + j][0];

    #pragma unroll 1
    for (int s = 0; s < NSTAGE; ++s) {
        const float* Cb = cb + (size_t)s * KCB * DDIM;
        const float* cn = ws + WS_CNORM + s * KCB;
        float bd[4]; int bi[4];
        #pragma unroll
        for (int i = 0; i < 4; ++i) { bd[i] = 1e30f; bi[i] = 0; }

        #pragma unroll 1
        for (int kc = 0; kc < NCHUNK; ++kc) {
            float dot[4][4];
            #pragma unroll
            for (int i = 0; i < 4; ++i)
                #pragma unroll
                for (int j = 0; j < 4; ++j) dot[i][j] = 0.f;

            #pragma unroll 1
            for (int dh = 0; dh < 2; ++dh) {
                __syncthreads();   // previous chunk/stage readers done
                const float* Cg = Cb + (size_t)kc * CHUNK * DDIM + dh * 64;
                #pragma unroll
                for (int j = 0; j < 4; ++j) {
                    int f4  = t + j * TPB;        // 0..1023
                    int row = f4 >> 4;            // 16 float4 per half-row
                    int c4  = f4 & 15;
                    float4 v = *(const float4*)(Cg + (size_t)row * DDIM + c4 * 4);
                    *(float4*)&Ct[row][c4 * 4] = v;
                }
                if (dh == 0 && t < CHUNK) sCn[t] = cn[kc * CHUNK + t];
                __syncthreads();

                #pragma unroll
                for (int d4 = 0; d4 < 16; ++d4) {
                    float4 r[4], c[4];
                    #pragma unroll
                    for (int i = 0; i < 4; ++i) r[i] = rp[i][dh * 16 + d4];
                    #pragma unroll
                    for (int j = 0; j < 4; ++j) c[j] = cp[j][d4];
                    #pragma unroll
                    for (int i = 0; i < 4; ++i)
                        #pragma unroll
                        for (int j = 0; j < 4; ++j) {
                            dot[i][j] += r[i].x * c[j].x;
                            dot[i][j] += r[i].y * c[j].y;
                            dot[i][j] += r[i].z * c[j].z;
                            dot[i][j] += r[i].w * c[j].w;
                        }
                }
            }

            // fold chunk into running argmin (strict <, k ascending => first occurrence)
            #pragma unroll
            for (int j = 0; j < 4; ++j) {
                int   kk  = kc * CHUNK + tc * 4 + j;
                float cnv = sCn[tc * 4 + j];
                #pragma unroll
                for (int i = 0; i < 4; ++i) {
                    float dist = cnv - 2.f * dot[i][j];
                    if (dist < bd[i]) { bd[i] = dist; bi[i] = kk; }
                }
            }
        }

        // cross-lane argmin over the 16 tc lanes (tie -> smaller index)
        #pragma unroll
        for (int m = 1; m < 16; m <<= 1) {
            #pragma unroll
            for (int i = 0; i < 4; ++i) {
                float od = __shfl_xor(bd[i], m);
                int   oi = __shfl_xor(bi[i], m);
                if (od < bd[i] || (od == bd[i] && oi < bi[i])) { bd[i] = od; bi[i] = oi; }
            }
        }
        if (tc == 0) {
            #pragma unroll
            for (int i = 0; i < 4; ++i) {
                int p = tp * 4 + i;
                sIdx[p] = bi[i];
                out[IDX_OFF + (n0 + p) * NSTAGE + s] = (float)bi[i];
            }
        }
        __syncthreads();

        // residual update + exact loss: diff = c - r_old; r_new = -diff
        {
            int p = t >> 2, q = t & 3;
            int idx = sIdx[p];
            const float4* cg = (const float4*)(Cb + (size_t)idx * DDIM);
            float la = 0.f;
            #pragma unroll
            for (int j = 0; j < 8; ++j) {
                int c4 = q + j * 4;
                float4 c = cg[c4];
                float4 r = *(float4*)&Rt[p][c4 * 4];
                float dx = c.x - r.x, dy = c.y - r.y, dz = c.z - r.z, dw = c.w - r.w;
                la += dx * dx + dy * dy + dz * dz + dw * dw;
                *(float4*)&Rt[p][c4 * 4] = make_float4(-dx, -dy, -dz, -dw);
            }
            lossAcc[s] += la;
        }
        __syncthreads();
    }

    // x_q = x - final residual (coalesced float4)
    float4* xq = (float4*)out;
    #pragma unroll
    for (int j = 0; j < 8; ++j) {
        int f4 = t + j * TPB;
        int p  = f4 >> 5;
        int d4 = f4 & 31;
        float4 xv = xblk[f4];
        float4 rv = *(const float4*)&Rt[p][d4 * 4];
        xq[n0 * (DDIM / 4) + f4] =
            make_float4(xv.x - rv.x, xv.y - rv.y, xv.z - rv.z, xv.w - rv.w);
    }

    // loss: wave reduce then one atomic per wave per stage
    #pragma unroll
    for (int m = 1; m < 64; m <<= 1) {
        #pragma unroll
        for (int s = 0; s < NSTAGE; ++s) lossAcc[s] += __shfl_xor(lossAcc[s], m);
    }
    if ((t & 63) == 0) {
        #pragma unroll
        for (int s = 0; s < NSTAGE; ++s) atomicAdd(&ws[WS_LOSS + s], lossAcc[s]);
    }
}

__global__ void rvq_finalize(const float* __restrict__ ws, float* __restrict__ out) {
    float sum = ws[0] + ws[1] + ws[2] + ws[3];
    // per stage: (1+beta)*sum_s/(N*D); mean over stages
    out[XQ_SIZE] = (1.f + BETA_F) * sum /
                   ((float)NSTAGE * (float)NPTS_TOTAL * (float)DDIM);
}

extern "C" void kernel_launch(void* const* d_in, const int* in_sizes, int n_in,
                              void* d_out, int out_size, void* d_ws, size_t ws_size,
                              hipStream_t stream) {
    const float* x  = (const float*)d_in[0];
    const float* cb = (const float*)d_in[1];
    float* out = (float*)d_out;
    float* ws  = (float*)d_ws;

    cnorm_init<<<(NSTAGE * KCB * 16) / TPB, TPB, 0, stream>>>(cb, ws);
    rvq_main<<<NPTS_TOTAL / PTS, TPB, 0, stream>>>(x, cb, out, ws);
    rvq_finalize<<<1, 1, 0, stream>>>(ws, out);
}

// Round 2
// 2090.260 us; speedup vs baseline: 1.6961x; 1.6961x over previous
//
#include <hip/hip_runtime.h>

// Residual VQ: N=65536 points, D=128, S=4 stages, K=2048 codewords.
// Outputs (flat, float32): x_q [N*D] @0, mean_loss @N*D, indices [N,S] as float @N*D+1.
//
// Round 2: kill LDS bank-conflict replays + go VALU-bound.
//  - Codeword->lane mapping interleaved (k = j*32 + tc): Ct b128 reads spread
//    across all 8 bank-quads (4 addrs/quad = data minimum, no replay).
//    Round 1 had all 16 addrs on 2 quads -> 4x replay -> 55% of kernel cycles.
//  - Register tile 8 pts x 4 cw (PTS=64, CHUNK=128): 12 b128 reads per 128
//    FMAs; r-reads are 2-address broadcasts (near-free).
//  - All inner-loop LDS addresses = thread base + compile-time immediate.

#define NPTS_TOTAL 65536
#define DDIM       128
#define NSTAGE     4
#define KCB        2048
#define BETA_F     0.25f

#define TPB    256
#define PTS    64          // points per block
#define CHUNK  128         // codewords per LDS chunk
#define NCHUNK (KCB / CHUNK)   // 16
#define LDR_R  132         // Rt row stride (floats) = 33 float4
#define LDR_C  68          // Ct row stride (floats) = 17 float4

#define WS_LOSS  0         // 4 floats
#define WS_CNORM 16        // NSTAGE*KCB floats

#define XQ_SIZE  (NPTS_TOTAL * DDIM)
#define IDX_OFF  (XQ_SIZE + 1)

__global__ void cnorm_init(const float* __restrict__ cb, float* __restrict__ ws) {
    int t = blockIdx.x * blockDim.x + threadIdx.x;   // 131072 threads
    int row = t >> 4;                                // 0..8191  (s*K + k)
    int q   = t & 15;
    const float4* rp = (const float4*)(cb + (size_t)row * DDIM);
    float s = 0.f;
    #pragma unroll
    for (int j = 0; j < 2; ++j) {
        float4 v = rp[q * 2 + j];
        s += v.x * v.x + v.y * v.y + v.z * v.z + v.w * v.w;
    }
    #pragma unroll
    for (int m = 1; m < 16; m <<= 1) s += __shfl_xor(s, m);
    if (q == 0) ws[WS_CNORM + row] = s;
    if (t < 4) ws[WS_LOSS + t] = 0.f;                // zero loss accumulators
}

__global__ __launch_bounds__(TPB, 2)
void rvq_main(const float* __restrict__ x, const float* __restrict__ cb,
              float* __restrict__ out, float* __restrict__ ws) {
    __shared__ float Rt[PTS][LDR_R];     // residual tile, full D      (33.8 KB)
    __shared__ float Ct[CHUNK][LDR_C];   // codeword half-chunk (64 d) (34.8 KB)
    __shared__ float sCn[CHUNK];
    __shared__ int   sIdx[PTS];

    const int t  = threadIdx.x;
    const int tc = t & 31;               // codeword lane: handles k = j*32+tc
    const int tp = t >> 5;               // point group:   handles p = tp*8+i
    const size_t n0 = (size_t)blockIdx.x * PTS;
    const float4* xblk = (const float4*)(x + n0 * DDIM);

    // load x tile -> Rt (coalesced float4)
    #pragma unroll
    for (int j = 0; j < 8; ++j) {
        int f4 = t + j * TPB;            // 0..2047
        int p  = f4 >> 5;                // 32 float4 per row
        int d4 = f4 & 31;
        float4 v = xblk[f4];
        *(float4*)&Rt[p][d4 * 4] = v;
    }

    float lossAcc[NSTAGE];
    #pragma unroll
    for (int s = 0; s < NSTAGE; ++s) lossAcc[s] = 0.f;

    // thread-base LDS pointers; all inner offsets are compile-time constants
    const float4* Rb = (const float4*)&Rt[tp * 8][0];   // + i*33 + dh*16 + d4
    const float4* Cb4 = (const float4*)&Ct[tc][0];      // + j*32*17 + d4

    #pragma unroll 1
    for (int s = 0; s < NSTAGE; ++s) {
        const float* Cbk = cb + (size_t)s * KCB * DDIM;
        const float* cn  = ws + WS_CNORM + s * KCB;
        float bd[8]; int bi[8];
        #pragma unroll
        for (int i = 0; i < 8; ++i) { bd[i] = 1e30f; bi[i] = 0; }

        #pragma unroll 1
        for (int kc = 0; kc < NCHUNK; ++kc) {
            float dot[8][4];
            #pragma unroll
            for (int i = 0; i < 8; ++i)
                #pragma unroll
                for (int j = 0; j < 4; ++j) dot[i][j] = 0.f;

            #pragma unroll 1
            for (int dh = 0; dh < 2; ++dh) {
                __syncthreads();   // previous chunk/stage readers done
                const float* Cg = Cbk + (size_t)kc * CHUNK * DDIM + dh * 64;
                #pragma unroll
                for (int j = 0; j < 8; ++j) {
                    int f4  = t + j * TPB;        // 0..2047
                    int row = f4 >> 4;            // 16 float4 per half-row
                    int c4  = f4 & 15;
                    float4 v = *(const float4*)(Cg + (size_t)row * DDIM + c4 * 4);
                    *(float4*)&Ct[row][c4 * 4] = v;
                }
                if (dh == 0 && t < CHUNK) sCn[t] = cn[kc * CHUNK + t];
                __syncthreads();

                #pragma unroll
                for (int d4 = 0; d4 < 16; ++d4) {
                    float4 r[8], c[4];
                    #pragma unroll
                    for (int j = 0; j < 4; ++j)
                        c[j] = Cb4[j * 32 * 17 + d4];          // imm offsets
                    #pragma unroll
                    for (int i = 0; i < 8; ++i)
                        r[i] = Rb[i * 33 + dh * 16 + d4];      // broadcast
                    #pragma unroll
                    for (int i = 0; i < 8; ++i)
                        #pragma unroll
                        for (int j = 0; j < 4; ++j) {
                            dot[i][j] += r[i].x * c[j].x;
                            dot[i][j] += r[i].y * c[j].y;
                            dot[i][j] += r[i].z * c[j].z;
                            dot[i][j] += r[i].w * c[j].w;
                        }
                }
            }

            // fold chunk into running argmin (strict <; k ascending within thread)
            #pragma unroll
            for (int j = 0; j < 4; ++j) {
                int   kk  = kc * CHUNK + j * 32 + tc;
                float cnv = sCn[j * 32 + tc];
                #pragma unroll
                for (int i = 0; i < 8; ++i) {
                    float dist = cnv - 2.f * dot[i][j];
                    if (dist < bd[i]) { bd[i] = dist; bi[i] = kk; }
                }
            }
        }

        // cross-lane argmin over the 32 tc lanes (tie -> smaller index)
        #pragma unroll
        for (int m = 1; m < 32; m <<= 1) {
            #pragma unroll
            for (int i = 0; i < 8; ++i) {
                float od = __shfl_xor(bd[i], m);
                int   oi = __shfl_xor(bi[i], m);
                if (od < bd[i] || (od == bd[i] && oi < bi[i])) { bd[i] = od; bi[i] = oi; }
            }
        }
        if (tc == 0) {
            #pragma unroll
            for (int i = 0; i < 8; ++i) {
                int p = tp * 8 + i;
                sIdx[p] = bi[i];
                out[IDX_OFF + (n0 + p) * NSTAGE + s] = (float)bi[i];
            }
        }
        __syncthreads();

        // residual update + exact loss: diff = c - r_old; r_new = -diff
        {
            int p = t >> 2, q = t & 3;
            int idx = sIdx[p];
            const float4* cg = (const float4*)(Cbk + (size_t)idx * DDIM);
            float la = 0.f;
            #pragma unroll
            for (int j = 0; j < 8; ++j) {
                int c4 = q + j * 4;
                float4 c = cg[c4];
                float4 r = *(float4*)&Rt[p][c4 * 4];
                float dx = c.x - r.x, dy = c.y - r.y, dz = c.z - r.z, dw = c.w - r.w;
                la += dx * dx + dy * dy + dz * dz + dw * dw;
                *(float4*)&Rt[p][c4 * 4] = make_float4(-dx, -dy, -dz, -dw);
            }
            lossAcc[s] += la;
        }
        __syncthreads();
    }

    // x_q = x - final residual (coalesced float4)
    float4* xq = (float4*)out;
    #pragma unroll
    for (int j = 0; j < 8; ++j) {
        int f4 = t + j * TPB;
        int p  = f4 >> 5;
        int d4 = f4 & 31;
        float4 xv = xblk[f4];
        float4 rv = *(const float4*)&Rt[p][d4 * 4];
        xq[n0 * (DDIM / 4) + f4] =
            make_float4(xv.x - rv.x, xv.y - rv.y, xv.z - rv.z, xv.w - rv.w);
    }

    // loss: wave reduce then one atomic per wave per stage
    #pragma unroll
    for (int m = 1; m < 64; m <<= 1) {
        #pragma unroll
        for (int s = 0; s < NSTAGE; ++s) lossAcc[s] += __shfl_xor(lossAcc[s], m);
    }
    if ((t & 63) == 0) {
        #pragma unroll
        for (int s = 0; s < NSTAGE; ++s) atomicAdd(&ws[WS_LOSS + s], lossAcc[s]);
    }
}

__global__ void rvq_finalize(const float* __restrict__ ws, float* __restrict__ out) {
    float sum = ws[0] + ws[1] + ws[2] + ws[3];
    // per stage: (1+beta)*sum_s/(N*D); mean over stages
    out[XQ_SIZE] = (1.f + BETA_F) * sum /
                   ((float)NSTAGE * (float)NPTS_TOTAL * (float)DDIM);
}

extern "C" void kernel_launch(void* const* d_in, const int* in_sizes, int n_in,
                              void* d_out, int out_size, void* d_ws, size_t ws_size,
                              hipStream_t stream) {
    const float* x  = (const float*)d_in[0];
    const float* cb = (const float*)d_in[1];
    float* out = (float*)d_out;
    float* ws  = (float*)d_ws;

    cnorm_init<<<(NSTAGE * KCB * 16) / TPB, TPB, 0, stream>>>(cb, ws);
    rvq_main<<<NPTS_TOTAL / PTS, TPB, 0, stream>>>(x, cb, out, ws);
    rvq_finalize<<<1, 1, 0, stream>>>(ws, out);
}

// Round 3
// 828.777 us; speedup vs baseline: 4.2778x; 2.5221x over previous
//
#include <hip/hip_runtime.h>

// Residual VQ via split-bf16 MFMA + exact fp32 recheck.
// N=65536 pts, D=128, S=4 stages, K=2048 codewords.
// Out (flat f32): x_q [N*D] @0, mean_loss @N*D, indices [N,S] as float @N*D+1.
//
// Per stage:
//  rvq_assign: dot(r, c) via 3-term split-bf16 MFMA (hi*hi + hi*lo + lo*hi,
//    |err| ~4e-4 in distance), track per-point approx top-2 candidates.
//    A-frags (residual hi/lo) register-resident for all of K; codebook
//    pre-packed in MFMA-frag-linear bf16 hi/lo order (ws), double-buffered
//    into LDS with global_load_lds(16B); ds_read_b128 lane-contiguous.
//  rvq_update: exact fp32 distance for both candidates (codebook L2-resident),
//    lexicographic (d, idx) argmin == numpy first-occurrence semantics,
//    fp32 residual update in-place in the x_q out region, loss accumulate.
//    Last stage writes x_q = x - r_new instead.

#define N_PTS   65536
#define DDIM    128
#define NSTAGE  4
#define KCB     2048
#define BETA_F  0.25f

#define XQ_SIZE (N_PTS * DDIM)
#define IDX_OFF (XQ_SIZE + 1)

// ws layout (float units)
#define WS_LOSS   0                        // 4 floats
#define WS_CN     16                       // NSTAGE*KCB floats
#define WS_CAND   (16 + NSTAGE * KCB)      // N_PTS*2 ints
#define WS_FRAG   (WS_CAND + N_PTS * 2)    // 16B-aligned (557120 B)
#define FRAG_S8_PER_STAGE (32 * 32 * 64)   // 65536 short8 = 1 MB per stage

typedef __attribute__((ext_vector_type(8))) short short8;
typedef __attribute__((ext_vector_type(4))) float f32x4;

__device__ inline short f2bf(float x) {            // RTNE bf16
    union { float f; unsigned u; } v; v.f = x;
    unsigned r = v.u + 0x7FFFu + ((v.u >> 16) & 1u);
    return (short)(r >> 16);
}
__device__ inline float bf2f(short h) {
    union { unsigned u; float f; } v; v.u = ((unsigned)(unsigned short)h) << 16;
    return v.f;
}
__device__ inline void gload_lds16(const void* g, void* l) {
    __builtin_amdgcn_global_load_lds(
        (const __attribute__((address_space(1))) unsigned int*)g,
        (__attribute__((address_space(3))) unsigned int*)l, 16, 0, 0);
}
__device__ inline void upd2(float& d1, int& i1, float& d2, int& i2, float d, int i) {
    bool lt1 = d < d1;
    bool lt2 = d < d2;
    float nd2 = lt1 ? d1 : (lt2 ? d : d2);
    int   ni2 = lt1 ? i1 : (lt2 ? i : i2);
    d1 = lt1 ? d : d1;  i1 = lt1 ? i : i1;
    d2 = nd2;           i2 = ni2;
}

// ||c||^2 per codeword + zero loss accumulators
__global__ void cnorm_init(const float* __restrict__ cb, float* __restrict__ ws) {
    int t = blockIdx.x * blockDim.x + threadIdx.x;   // 131072 threads
    int row = t >> 4;                                // 0..8191 (s*K + k)
    int q   = t & 15;
    const float4* rp = (const float4*)(cb + (size_t)row * DDIM);
    float s = 0.f;
    #pragma unroll
    for (int j = 0; j < 2; ++j) {
        float4 v = rp[q * 2 + j];
        s += v.x * v.x + v.y * v.y + v.z * v.z + v.w * v.w;
    }
    #pragma unroll
    for (int m = 1; m < 16; m <<= 1) s += __shfl_xor(s, m);
    if (q == 0) ws[WS_CN + row] = s;
    if (t < 4) ws[WS_LOSS + t] = 0.f;
}

// Pack codebook into MFMA-B-frag-linear bf16 hi/lo layout:
// id = (((s*32 + c)*4 + nt)*4 + kk)*2*64 + h*64 + lane ; 16 B per id.
// lane's 8 bf16 = cb[s][c*64 + nt*16 + (lane&15)][kk*32 + (lane>>4)*8 .. +8]
__global__ void frag_pack(const float* __restrict__ cb, float* __restrict__ ws) {
    int id   = blockIdx.x * 256 + threadIdx.x;       // 0..262143
    int lane = id & 63;
    int h    = (id >> 6) & 1;
    int kk   = (id >> 7) & 3;
    int nt   = (id >> 9) & 3;
    int c    = (id >> 11) & 31;
    int s    = (id >> 16);
    int row  = c * 64 + nt * 16 + (lane & 15);
    int koff = kk * 32 + (lane >> 4) * 8;
    const float* src = cb + ((size_t)(s * KCB + row) * DDIM + koff);
    short8 v;
    #pragma unroll
    for (int j = 0; j < 8; ++j) {
        float xv = src[j];
        short hi = f2bf(xv);
        if (h) { v[j] = f2bf(xv - bf2f(hi)); }
        else   { v[j] = hi; }
    }
    ((short8*)(ws + WS_FRAG))[id] = v;
}

// Approx top-2 assignment. Block = 256 thr = 4 waves x 32 pts.
__global__ __launch_bounds__(256, 2)
void rvq_assign(const float* __restrict__ rsrc, float* __restrict__ ws,
                int stage, int* __restrict__ cand) {
    __shared__ short8 Bbuf[2][2048];                 // 2 x 32 KB
    const int t    = threadIdx.x;
    const int lane = t & 63;
    const int w    = t >> 6;
    const int p0   = blockIdx.x * 128 + w * 32;

    const short8* frag = (const short8*)(ws + WS_FRAG)
                       + (size_t)stage * FRAG_S8_PER_STAGE;
    const float* cn = ws + WS_CN + stage * KCB;

    // Build register-resident A fragments (hi/lo), reused for all of K.
    // A[m][k]: m = lane&15 -> point p0 + mt*16 + (lane&15);
    //          k = kk*32 + (lane>>4)*8 + j
    short8 Ahi[2][4], Alo[2][4];
    #pragma unroll
    for (int mt = 0; mt < 2; ++mt)
        #pragma unroll
        for (int kk = 0; kk < 4; ++kk) {
            const float* rp = rsrc
                + (size_t)(p0 + mt * 16 + (lane & 15)) * DDIM
                + kk * 32 + (lane >> 4) * 8;
            float4 v0 = *(const float4*)rp;
            float4 v1 = *(const float4*)(rp + 4);
            float xv[8] = {v0.x, v0.y, v0.z, v0.w, v1.x, v1.y, v1.z, v1.w};
            short8 hi8, lo8;
            #pragma unroll
            for (int j = 0; j < 8; ++j) {
                short hi = f2bf(xv[j]);
                hi8[j] = hi;
                lo8[j] = f2bf(xv[j] - bf2f(hi));
            }
            Ahi[mt][kk] = hi8;
            Alo[mt][kk] = lo8;
        }

    float d1[8], d2[8]; int i1[8], i2[8];
    #pragma unroll
    for (int p = 0; p < 8; ++p) { d1[p] = 3.0e38f; d2[p] = 3.0e38f; i1[p] = 0; i2[p] = 1; }

    // prefetch chunk 0
    #pragma unroll
    for (int j = 0; j < 8; ++j) {
        int idx = t + j * 256;
        gload_lds16(frag + idx, &Bbuf[0][idx]);
    }

    #pragma unroll 1
    for (int c = 0; c < 32; ++c) {
        __syncthreads();                     // drains vmcnt: chunk c resident
        if (c + 1 < 32) {                    // prefetch next into other buffer
            const short8* src = frag + (size_t)(c + 1) * 2048;
            #pragma unroll
            for (int j = 0; j < 8; ++j) {
                int idx = t + j * 256;
                gload_lds16(src + idx, &Bbuf[(c + 1) & 1][idx]);
            }
        }
        const short8* B = Bbuf[c & 1];
        const int cwbase = c * 64;
        #pragma unroll
        for (int nt = 0; nt < 4; ++nt) {
            f32x4 acc0 = {0.f, 0.f, 0.f, 0.f};
            f32x4 acc1 = {0.f, 0.f, 0.f, 0.f};
            #pragma unroll
            for (int kk = 0; kk < 4; ++kk) {
                short8 bh = B[((nt * 4 + kk) * 2 + 0) * 64 + lane];
                short8 bl = B[((nt * 4 + kk) * 2 + 1) * 64 + lane];
                acc0 = __builtin_amdgcn_mfma_f32_16x16x32_bf16(Ahi[0][kk], bh, acc0, 0, 0, 0);
                acc1 = __builtin_amdgcn_mfma_f32_16x16x32_bf16(Ahi[1][kk], bh, acc1, 0, 0, 0);
                acc0 = __builtin_amdgcn_mfma_f32_16x16x32_bf16(Alo[0][kk], bh, acc0, 0, 0, 0);
                acc1 = __builtin_amdgcn_mfma_f32_16x16x32_bf16(Alo[1][kk], bh, acc1, 0, 0, 0);
                acc0 = __builtin_amdgcn_mfma_f32_16x16x32_bf16(Ahi[0][kk], bl, acc0, 0, 0, 0);
                acc1 = __builtin_amdgcn_mfma_f32_16x16x32_bf16(Ahi[1][kk], bl, acc1, 0, 0, 0);
            }
            // D layout: col n = lane&15 (codeword), row m = (lane>>4)*4 + reg
            int   cw  = cwbase + nt * 16 + (lane & 15);
            float cnv = cn[cw];
            #pragma unroll
            for (int r = 0; r < 4; ++r) {
                float da = cnv - 2.f * acc0[r];
                upd2(d1[r], i1[r], d2[r], i2[r], da, cw);
                float db = cnv - 2.f * acc1[r];
                upd2(d1[4 + r], i1[4 + r], d2[4 + r], i2[4 + r], db, cw);
            }
        }
    }

    // merge per-lane top-2 across the 16 lanes sharing each point row
    #pragma unroll
    for (int m = 1; m < 16; m <<= 1) {
        #pragma unroll
        for (int p = 0; p < 8; ++p) {
            float od1 = __shfl_xor(d1[p], m); int oi1 = __shfl_xor(i1[p], m);
            float od2 = __shfl_xor(d2[p], m); int oi2 = __shfl_xor(i2[p], m);
            upd2(d1[p], i1[p], d2[p], i2[p], od1, oi1);
            upd2(d1[p], i1[p], d2[p], i2[p], od2, oi2);
        }
    }
    if ((lane & 15) == 0) {
        #pragma unroll
        for (int p = 0; p < 8; ++p) {
            int point = p0 + (p >> 2) * 16 + (lane >> 4) * 4 + (p & 3);
            cand[point * 2]     = i1[p];
            cand[point * 2 + 1] = i2[p];
        }
    }
}

// Exact recheck + residual update. Block = 256 thr = 64 pts x 4 thr.
__global__ __launch_bounds__(256)
void rvq_update(const float* __restrict__ rsrc, const float* __restrict__ cb,
                const float* __restrict__ x, float* __restrict__ ws,
                const int* __restrict__ cand, float* __restrict__ out, int stage) {
    const int t  = threadIdx.x;
    const int q  = t & 3;
    const int p  = blockIdx.x * 64 + (t >> 2);
    const float* cbs = cb + (size_t)stage * KCB * DDIM;
    const float* cn  = ws + WS_CN + stage * KCB;

    const float4* rp = (const float4*)(rsrc + (size_t)p * DDIM + q * 32);
    float4 r[8], ca[8], cbv[8];
    int ia = cand[p * 2], ib = cand[p * 2 + 1];
    const float4* pa = (const float4*)(cbs + (size_t)ia * DDIM + q * 32);
    const float4* pb = (const float4*)(cbs + (size_t)ib * DDIM + q * 32);
    float da = 0.f, db = 0.f;
    #pragma unroll
    for (int j = 0; j < 8; ++j) {
        r[j] = rp[j]; ca[j] = pa[j]; cbv[j] = pb[j];
        da += r[j].x * ca[j].x + r[j].y * ca[j].y + r[j].z * ca[j].z + r[j].w * ca[j].w;
        db += r[j].x * cbv[j].x + r[j].y * cbv[j].y + r[j].z * cbv[j].z + r[j].w * cbv[j].w;
    }
    da += __shfl_xor(da, 1); da += __shfl_xor(da, 2);
    db += __shfl_xor(db, 1); db += __shfl_xor(db, 2);
    float dA = cn[ia] - 2.f * da;
    float dB = cn[ib] - 2.f * db;
    bool bw = (dB < dA) || (dB == dA && ib < ia);   // lexicographic (d, idx)
    int  wi = bw ? ib : ia;

    float la = 0.f;
    float* rd = out + (size_t)p * DDIM + q * 32;    // x_q region doubles as residual
    const float4* xp = (const float4*)(x + (size_t)p * DDIM + q * 32);
    #pragma unroll
    for (int j = 0; j < 8; ++j) {
        float4 c  = bw ? cbv[j] : ca[j];
        float dx = c.x - r[j].x, dy = c.y - r[j].y, dz = c.z - r[j].z, dw = c.w - r[j].w;
        la += dx * dx + dy * dy + dz * dz + dw * dw;
        float4 rn = make_float4(-dx, -dy, -dz, -dw);     // r_new = r - c
        if (stage == NSTAGE - 1) {
            float4 xv = xp[j];
            ((float4*)rd)[j] = make_float4(xv.x - rn.x, xv.y - rn.y,
                                           xv.z - rn.z, xv.w - rn.w);
        } else {
            ((float4*)rd)[j] = rn;
        }
    }
    if (q == 0) out[IDX_OFF + (size_t)p * NSTAGE + stage] = (float)wi;

    #pragma unroll
    for (int m = 1; m < 64; m <<= 1) la += __shfl_xor(la, m);
    if ((t & 63) == 0) atomicAdd(ws + WS_LOSS + stage, la);
}

__global__ void rvq_finalize(const float* __restrict__ ws, float* __restrict__ out) {
    float sum = ws[0] + ws[1] + ws[2] + ws[3];
    out[XQ_SIZE] = (1.f + BETA_F) * sum /
                   ((float)NSTAGE * (float)N_PTS * (float)DDIM);
}

extern "C" void kernel_launch(void* const* d_in, const int* in_sizes, int n_in,
                              void* d_out, int out_size, void* d_ws, size_t ws_size,
                              hipStream_t stream) {
    const float* x  = (const float*)d_in[0];
    const float* cb = (const float*)d_in[1];
    float* out = (float*)d_out;
    float* ws  = (float*)d_ws;
    int*   cand = (int*)(ws + WS_CAND);

    cnorm_init<<<512, 256, 0, stream>>>(cb, ws);
    frag_pack<<<1024, 256, 0, stream>>>(cb, ws);
    for (int s = 0; s < NSTAGE; ++s) {
        const float* rsrc = (s == 0) ? x : out;   // residual lives in x_q region
        rvq_assign<<<512, 256, 0, stream>>>(rsrc, ws, s, cand);
        rvq_update<<<N_PTS / 64, 256, 0, stream>>>(rsrc, cb, x, ws, cand, out, s);
    }
    rvq_finalize<<<1, 1, 0, stream>>>(ws, out);
}

// Round 5
// 680.179 us; speedup vs baseline: 5.2124x; 1.2185x over previous
//
#include <hip/hip_runtime.h>

// Residual VQ, fully fused, exact-fp32 residual chain.
// N=65536 pts, D=128, S=4 stages, K=2048 codewords.
// Out (flat f32): x_q [N*D] @0, mean_loss @N*D, indices [N,S] as float @N*D+1.
//
// Per lane: one point. Exact fp32 residual R[4][8] in registers (the round-3
// semantics that passed); bf16 hi/lo A-frags re-derived from R each stage.
// Per stage: stream pre-packed codebook frags (2 MB) through LDS (32 KB
// double-buffered global_load_lds w16), 3-term split-bf16 MFMA -> approx
// top-2 per point -> exact fp32 recheck of both candidates against R ->
// winner (lexicographic (d,idx) = numpy first-occurrence), loss = d_win +
// ||R||^2, exact update R -= c_win. Last stage writes x_q = x - R.

#define N_PTS   65536
#define DDIM    128
#define NSTAGE  4
#define KCB     2048
#define BETA_F  0.25f

#define XQ_SIZE (N_PTS * DDIM)
#define IDX_OFF (XQ_SIZE + 1)

// ws layout (float units)
#define WS_LOSS 0                         // 4 floats
#define WS_CN   16                        // NSTAGE*KCB floats
#define WS_FRAG (16 + NSTAGE * KCB)       // frag stream, 16B-aligned
#define FRAG_S8 (32 * 32 * 64)            // short8 per stage = 65536 (1 MB)

typedef __attribute__((ext_vector_type(8))) short short8;
typedef __attribute__((ext_vector_type(4))) float f32x4;

__device__ inline short f2bf(float x) {            // RTNE bf16
    union { float f; unsigned u; } v; v.f = x;
    unsigned r = v.u + 0x7FFFu + ((v.u >> 16) & 1u);
    return (short)(r >> 16);
}
__device__ inline float bf2f(short h) {
    union { unsigned u; float f; } v; v.u = ((unsigned)(unsigned short)h) << 16;
    return v.f;
}
__device__ inline void gload_lds16(const void* g, void* l) {
    __builtin_amdgcn_global_load_lds(
        (const __attribute__((address_space(1))) unsigned int*)g,
        (__attribute__((address_space(3))) unsigned int*)l, 16, 0, 0);
}
__device__ inline void upd2(float& d1, int& i1, float& d2, int& i2, float d, int i) {
    bool lt1 = d < d1;
    bool lt2 = d < d2;
    float nd2 = lt1 ? d1 : (lt2 ? d : d2);
    int   ni2 = lt1 ? i1 : (lt2 ? i : i2);
    d1 = lt1 ? d : d1;  i1 = lt1 ? i : i1;
    d2 = nd2;           i2 = ni2;
}

// ||c||^2 per codeword + zero loss accumulators
__global__ void cnorm_init(const float* __restrict__ cb, float* __restrict__ ws) {
    int t = blockIdx.x * blockDim.x + threadIdx.x;   // 131072 threads
    int row = t >> 4;                                // 0..8191 (s*K + k)
    int q   = t & 15;
    const float4* rp = (const float4*)(cb + (size_t)row * DDIM);
    float s = 0.f;
    #pragma unroll
    for (int j = 0; j < 2; ++j) {
        float4 v = rp[q * 2 + j];
        s += v.x * v.x + v.y * v.y + v.z * v.z + v.w * v.w;
    }
    #pragma unroll
    for (int m = 1; m < 16; m <<= 1) s += __shfl_xor(s, m);
    if (q == 0) ws[WS_CN + row] = s;
    if (t < 4) ws[WS_LOSS + t] = 0.f;
}

// Pack codebook into MFMA-B-frag-linear bf16 hi/lo layout:
// id = (((s*32 + c)*4 + nt)*4 + kk)*2*64 + h*64 + lane ; 16 B per id.
// lane's 8 bf16 = cb[s][c*64 + nt*16 + (lane&15)][kk*32 + (lane>>4)*8 .. +8]
__global__ void frag_pack(const float* __restrict__ cb, float* __restrict__ ws) {
    int id   = blockIdx.x * 256 + threadIdx.x;       // 0..262143
    int lane = id & 63;
    int h    = (id >> 6) & 1;
    int kk   = (id >> 7) & 3;
    int nt   = (id >> 9) & 3;
    int c    = (id >> 11) & 31;
    int s    = (id >> 16);
    int row  = c * 64 + nt * 16 + (lane & 15);
    int koff = kk * 32 + (lane >> 4) * 8;
    const float* src = cb + ((size_t)(s * KCB + row) * DDIM + koff);
    short8 v;
    #pragma unroll
    for (int j = 0; j < 8; ++j) {
        float xv = src[j];
        short hi = f2bf(xv);
        if (h) { v[j] = f2bf(xv - bf2f(hi)); }
        else   { v[j] = hi; }
    }
    ((short8*)(ws + WS_FRAG))[id] = v;
}

__global__ __launch_bounds__(512, 4)
void rvq_fused(const float* __restrict__ x, const float* __restrict__ cb,
               float* __restrict__ ws, float* __restrict__ out) {
    __shared__ short8 Bbuf[2][2048];                 // 2 x 32 KB
    __shared__ int sC1[128], sC2[128];

    const int t    = threadIdx.x;
    const int lane = t & 63;
    const int w    = t >> 6;                         // wave 0..7
    const int m    = lane & 15;
    const int q    = lane >> 4;
    const size_t myp = (size_t)blockIdx.x * 128 + w * 16 + m;  // lane's point

    const short8* fragAll = (const short8*)(ws + WS_FRAG);

    // Exact fp32 residual R (round-3 semantics) + split-bf16 A-frags.
    // A[m][k]: row m = lane&15 (point), k = kk*32 + q*8 + j.
    float  R[4][8];
    short8 Ahi[4], Alo[4];
    #pragma unroll
    for (int kk = 0; kk < 4; ++kk) {
        const float* rp = x + myp * DDIM + kk * 32 + q * 8;
        float4 v0 = *(const float4*)rp;
        float4 v1 = *(const float4*)(rp + 4);
        R[kk][0] = v0.x; R[kk][1] = v0.y; R[kk][2] = v0.z; R[kk][3] = v0.w;
        R[kk][4] = v1.x; R[kk][5] = v1.y; R[kk][6] = v1.z; R[kk][7] = v1.w;
        short8 hi8, lo8;
        #pragma unroll
        for (int j = 0; j < 8; ++j) {
            short hi = f2bf(R[kk][j]);
            hi8[j] = hi;
            lo8[j] = f2bf(R[kk][j] - bf2f(hi));
        }
        Ahi[kk] = hi8; Alo[kk] = lo8;
    }

    float lossAcc[NSTAGE] = {0.f, 0.f, 0.f, 0.f};

    // prefetch stage 0 chunk 0
    #pragma unroll
    for (int j = 0; j < 4; ++j) {
        int idx = t + j * 512;
        gload_lds16(fragAll + idx, &Bbuf[0][idx]);
    }

    #pragma unroll 1
    for (int s = 0; s < NSTAGE; ++s) {
        const short8* frag = fragAll + (size_t)s * FRAG_S8;
        const float*  cn   = ws + WS_CN + s * KCB;
        const float*  cbs  = cb + (size_t)s * KCB * DDIM;

        float d1[4], d2[4]; int i1[4], i2[4];
        #pragma unroll
        for (int r = 0; r < 4; ++r) { d1[r] = 3e38f; d2[r] = 3e38f; i1[r] = 0; i2[r] = 1; }

        #pragma unroll 1
        for (int c = 0; c < 32; ++c) {
            __syncthreads();                 // buf[c&1] resident; prev readers done
            if (c + 1 < 32) {
                const short8* src = frag + (size_t)(c + 1) * 2048;
                #pragma unroll
                for (int j = 0; j < 4; ++j) {
                    int idx = t + j * 512;
                    gload_lds16(src + idx, &Bbuf[(c + 1) & 1][idx]);
                }
            } else if (s + 1 < NSTAGE) {     // cross-stage prefetch into buf0
                const short8* src = frag + FRAG_S8;
                #pragma unroll
                for (int j = 0; j < 4; ++j) {
                    int idx = t + j * 512;
                    gload_lds16(src + idx, &Bbuf[0][idx]);
                }
            }
            const short8* B = Bbuf[c & 1];
            #pragma unroll
            for (int np = 0; np < 2; ++np) { // two interleaved nt chains
                int cw0 = c * 64 + np * 32 + m;
                float cnv0 = cn[cw0];
                float cnv1 = cn[cw0 + 16];
                f32x4 acc0 = {0.f, 0.f, 0.f, 0.f};
                f32x4 acc1 = {0.f, 0.f, 0.f, 0.f};
                #pragma unroll
                for (int kk = 0; kk < 4; ++kk) {
                    short8 bh0 = B[(((np * 2 + 0) * 4 + kk) * 2 + 0) * 64 + lane];
                    short8 bl0 = B[(((np * 2 + 0) * 4 + kk) * 2 + 1) * 64 + lane];
                    short8 bh1 = B[(((np * 2 + 1) * 4 + kk) * 2 + 0) * 64 + lane];
                    short8 bl1 = B[(((np * 2 + 1) * 4 + kk) * 2 + 1) * 64 + lane];
                    acc0 = __builtin_amdgcn_mfma_f32_16x16x32_bf16(Ahi[kk], bh0, acc0, 0, 0, 0);
                    acc1 = __builtin_amdgcn_mfma_f32_16x16x32_bf16(Ahi[kk], bh1, acc1, 0, 0, 0);
                    acc0 = __builtin_amdgcn_mfma_f32_16x16x32_bf16(Alo[kk], bh0, acc0, 0, 0, 0);
                    acc1 = __builtin_amdgcn_mfma_f32_16x16x32_bf16(Alo[kk], bh1, acc1, 0, 0, 0);
                    acc0 = __builtin_amdgcn_mfma_f32_16x16x32_bf16(Ahi[kk], bl0, acc0, 0, 0, 0);
                    acc1 = __builtin_amdgcn_mfma_f32_16x16x32_bf16(Ahi[kk], bl1, acc1, 0, 0, 0);
                }
                // D layout: col = lane&15 (codeword), row(point) = q*4 + reg
                #pragma unroll
                for (int r = 0; r < 4; ++r) {
                    float da = cnv0 - 2.f * acc0[r];
                    upd2(d1[r], i1[r], d2[r], i2[r], da, cw0);
                    float db = cnv1 - 2.f * acc1[r];
                    upd2(d1[r], i1[r], d2[r], i2[r], db, cw0 + 16);
                }
            }
        }

        // merge top-2 across the 16 codeword columns
        #pragma unroll
        for (int mm = 1; mm < 16; mm <<= 1) {
            #pragma unroll
            for (int r = 0; r < 4; ++r) {
                float od1 = __shfl_xor(d1[r], mm); int oi1 = __shfl_xor(i1[r], mm);
                float od2 = __shfl_xor(d2[r], mm); int oi2 = __shfl_xor(i2[r], mm);
                upd2(d1[r], i1[r], d2[r], i2[r], od1, oi1);
                upd2(d1[r], i1[r], d2[r], i2[r], od2, oi2);
            }
        }
        if (m == 0) {                        // redistribute: D rows -> A rows
            #pragma unroll
            for (int r = 0; r < 4; ++r) {
                int pt = q * 4 + r;
                sC1[w * 16 + pt] = i1[r];
                sC2[w * 16 + pt] = i2[r];
            }
        }
        __syncthreads();

        int ia = sC1[w * 16 + m];
        int ib = sC2[w * 16 + m];

        // exact fp32 recheck against R: lane covers k = kk*32 + q*8 .. +8
        float pa = 0.f, pb = 0.f, pr = 0.f;
        #pragma unroll
        for (int kk = 0; kk < 4; ++kk) {
            const float* pav = cbs + (size_t)ia * DDIM + kk * 32 + q * 8;
            const float* pbv = cbs + (size_t)ib * DDIM + kk * 32 + q * 8;
            float4 a0 = *(const float4*)pav, a1 = *(const float4*)(pav + 4);
            float4 b0 = *(const float4*)pbv, b1 = *(const float4*)(pbv + 4);
            float av[8] = {a0.x, a0.y, a0.z, a0.w, a1.x, a1.y, a1.z, a1.w};
            float bv[8] = {b0.x, b0.y, b0.z, b0.w, b1.x, b1.y, b1.z, b1.w};
            #pragma unroll
            for (int j = 0; j < 8; ++j) {
                float rv = R[kk][j];
                pa += rv * av[j];
                pb += rv * bv[j];
                pr += rv * rv;
            }
        }
        pa += __shfl_xor(pa, 16); pa += __shfl_xor(pa, 32);
        pb += __shfl_xor(pb, 16); pb += __shfl_xor(pb, 32);
        pr += __shfl_xor(pr, 16); pr += __shfl_xor(pr, 32);
        float dA = cn[ia] - 2.f * pa;
        float dB = cn[ib] - 2.f * pb;
        bool bw = (dB < dA) || (dB == dA && ib < ia);   // first-occurrence
        int  wi = bw ? ib : ia;
        if (q == 0) {
            out[IDX_OFF + myp * NSTAGE + s] = (float)wi;
            lossAcc[s] += (bw ? dB : dA) + pr;           // ||c - r||^2
        }

        // exact update: R -= c_win; re-split frags; last stage: x_q = x - R
        const float* cwr = cbs + (size_t)wi * DDIM;
        #pragma unroll
        for (int kk = 0; kk < 4; ++kk) {
            const float* pwv = cwr + kk * 32 + q * 8;
            float4 w0 = *(const float4*)pwv, w1 = *(const float4*)(pwv + 4);
            float wv[8] = {w0.x, w0.y, w0.z, w0.w, w1.x, w1.y, w1.z, w1.w};
            short8 hi8, lo8;
            #pragma unroll
            for (int j = 0; j < 8; ++j) {
                float v = R[kk][j] - wv[j];
                R[kk][j] = v;
                short hi = f2bf(v);
                hi8[j] = hi;
                lo8[j] = f2bf(v - bf2f(hi));
            }
            Ahi[kk] = hi8; Alo[kk] = lo8;
            if (s == NSTAGE - 1) {
                const float* xp = x + myp * DDIM + kk * 32 + q * 8;
                float4 x0 = *(const float4*)xp, x1 = *(const float4*)(xp + 4);
                float* op = out + myp * DDIM + kk * 32 + q * 8;
                *(float4*)op = make_float4(x0.x - R[kk][0], x0.y - R[kk][1],
                                           x0.z - R[kk][2], x0.w - R[kk][3]);
                *(float4*)(op + 4) = make_float4(x1.x - R[kk][4], x1.y - R[kk][5],
                                                 x1.z - R[kk][6], x1.w - R[kk][7]);
            }
        }
    }

    // loss: wave reduce, one atomic per wave per stage
    #pragma unroll
    for (int mm = 1; mm < 64; mm <<= 1)
        #pragma unroll
        for (int s2 = 0; s2 < NSTAGE; ++s2)
            lossAcc[s2] += __shfl_xor(lossAcc[s2], mm);
    if (lane == 0)
        #pragma unroll
        for (int s2 = 0; s2 < NSTAGE; ++s2)
            atomicAdd(ws + WS_LOSS + s2, lossAcc[s2]);
}

__global__ void rvq_finalize(const float* __restrict__ ws, float* __restrict__ out) {
    float sum = ws[0] + ws[1] + ws[2] + ws[3];
    out[XQ_SIZE] = (1.f + BETA_F) * sum /
                   ((float)NSTAGE * (float)N_PTS * (float)DDIM);
}

extern "C" void kernel_launch(void* const* d_in, const int* in_sizes, int n_in,
                              void* d_out, int out_size, void* d_ws, size_t ws_size,
                              hipStream_t stream) {
    const float* x  = (const float*)d_in[0];
    const float* cb = (const float*)d_in[1];
    float* out = (float*)d_out;
    float* ws  = (float*)d_ws;

    cnorm_init<<<512, 256, 0, stream>>>(cb, ws);
    frag_pack<<<1024, 256, 0, stream>>>(cb, ws);
    rvq_fused<<<512, 512, 0, stream>>>(x, cb, ws, out);
    rvq_finalize<<<1, 1, 0, stream>>>(ws, out);
}

// Round 6
// 654.775 us; speedup vs baseline: 5.4146x; 1.0388x over previous
//
#include <hip/hip_runtime.h>

// Residual VQ, fully fused, exact-fp32 residual chain, 2x M-blocked MFMA.
// N=65536 pts, D=128, S=4 stages, K=2048 codewords.
// Out (flat f32): x_q [N*D] @0, mean_loss @N*D, indices [N,S] as float @N*D+1.
//
// 256-thr blocks (4 waves), 32 pts/wave as two 16-row M-tiles: each LDS
// B-frag pair (bh,bl) feeds 6 MFMAs (3-term split-bf16 x 2 tiles), halving
// LDS read traffic vs round 5. ||c||^2 staged in LDS per stage. Exact fp32
// residual R in registers; approx top-2 -> exact recheck -> winner (numpy
// first-occurrence), loss = d_win + ||R||^2, exact R -= c_win.

#define N_PTS   65536
#define DDIM    128
#define NSTAGE  4
#define KCB     2048
#define BETA_F  0.25f

#define XQ_SIZE (N_PTS * DDIM)
#define IDX_OFF (XQ_SIZE + 1)

// ws layout (float units)
#define WS_LOSS 0                         // 4 floats
#define WS_CN   16                        // NSTAGE*KCB floats
#define WS_FRAG (16 + NSTAGE * KCB)       // frag stream, 16B-aligned
#define FRAG_S8 (32 * 32 * 64)            // short8 per stage = 65536 (1 MB)

typedef __attribute__((ext_vector_type(8))) short short8;
typedef __attribute__((ext_vector_type(4))) float f32x4;

__device__ inline short f2bf(float x) {            // RTNE bf16
    union { float f; unsigned u; } v; v.f = x;
    unsigned r = v.u + 0x7FFFu + ((v.u >> 16) & 1u);
    return (short)(r >> 16);
}
__device__ inline float bf2f(short h) {
    union { unsigned u; float f; } v; v.u = ((unsigned)(unsigned short)h) << 16;
    return v.f;
}
__device__ inline void gload_lds16(const void* g, void* l) {
    __builtin_amdgcn_global_load_lds(
        (const __attribute__((address_space(1))) unsigned int*)g,
        (__attribute__((address_space(3))) unsigned int*)l, 16, 0, 0);
}
__device__ inline void upd2(float& d1, int& i1, float& d2, int& i2, float d, int i) {
    bool lt1 = d < d1;
    bool lt2 = d < d2;
    float nd2 = lt1 ? d1 : (lt2 ? d : d2);
    int   ni2 = lt1 ? i1 : (lt2 ? i : i2);
    d1 = lt1 ? d : d1;  i1 = lt1 ? i : i1;
    d2 = nd2;           i2 = ni2;
}

// ||c||^2 per codeword + zero loss accumulators
__global__ void cnorm_init(const float* __restrict__ cb, float* __restrict__ ws) {
    int t = blockIdx.x * blockDim.x + threadIdx.x;   // 131072 threads
    int row = t >> 4;                                // 0..8191 (s*K + k)
    int q   = t & 15;
    const float4* rp = (const float4*)(cb + (size_t)row * DDIM);
    float s = 0.f;
    #pragma unroll
    for (int j = 0; j < 2; ++j) {
        float4 v = rp[q * 2 + j];
        s += v.x * v.x + v.y * v.y + v.z * v.z + v.w * v.w;
    }
    #pragma unroll
    for (int m = 1; m < 16; m <<= 1) s += __shfl_xor(s, m);
    if (q == 0) ws[WS_CN + row] = s;
    if (t < 4) ws[WS_LOSS + t] = 0.f;
}

// Pack codebook into MFMA-B-frag-linear bf16 hi/lo layout:
// id = (((s*32 + c)*4 + nt)*4 + kk)*2*64 + h*64 + lane ; 16 B per id.
// lane's 8 bf16 = cb[s][c*64 + nt*16 + (lane&15)][kk*32 + (lane>>4)*8 .. +8]
__global__ void frag_pack(const float* __restrict__ cb, float* __restrict__ ws) {
    int id   = blockIdx.x * 256 + threadIdx.x;       // 0..262143
    int lane = id & 63;
    int h    = (id >> 6) & 1;
    int kk   = (id >> 7) & 3;
    int nt   = (id >> 9) & 3;
    int c    = (id >> 11) & 31;
    int s    = (id >> 16);
    int row  = c * 64 + nt * 16 + (lane & 15);
    int koff = kk * 32 + (lane >> 4) * 8;
    const float* src = cb + ((size_t)(s * KCB + row) * DDIM + koff);
    short8 v;
    #pragma unroll
    for (int j = 0; j < 8; ++j) {
        float xv = src[j];
        short hi = f2bf(xv);
        if (h) { v[j] = f2bf(xv - bf2f(hi)); }
        else   { v[j] = hi; }
    }
    ((short8*)(ws + WS_FRAG))[id] = v;
}

__global__ __launch_bounds__(256, 2)
void rvq_fused(const float* __restrict__ x, const float* __restrict__ cb,
               float* __restrict__ ws, float* __restrict__ out) {
    __shared__ short8 Bbuf[2][2048];                 // 2 x 32 KB
    __shared__ float  sCn[KCB];                      // 8 KB, per-stage ||c||^2
    __shared__ int    sC1[128], sC2[128];

    const int t    = threadIdx.x;
    const int lane = t & 63;
    const int w    = t >> 6;                         // wave 0..3
    const int m    = lane & 15;
    const int q    = lane >> 4;
    const size_t pbase = (size_t)blockIdx.x * 128 + w * 32;  // wave's 32 points
    const size_t pt[2] = {pbase + m, pbase + 16 + m};

    const short8* fragAll = (const short8*)(ws + WS_FRAG);

    // Exact fp32 residual R + split-bf16 A-frags, 2 M-tiles.
    // A[tile][m][k]: row m = point pt[tile], k = kk*32 + q*8 + j.
    float  R[2][4][8];
    short8 Ahi[2][4], Alo[2][4];
    #pragma unroll
    for (int tile = 0; tile < 2; ++tile)
        #pragma unroll
        for (int kk = 0; kk < 4; ++kk) {
            const float* rp = x + pt[tile] * DDIM + kk * 32 + q * 8;
            float4 v0 = *(const float4*)rp;
            float4 v1 = *(const float4*)(rp + 4);
            R[tile][kk][0] = v0.x; R[tile][kk][1] = v0.y;
            R[tile][kk][2] = v0.z; R[tile][kk][3] = v0.w;
            R[tile][kk][4] = v1.x; R[tile][kk][5] = v1.y;
            R[tile][kk][6] = v1.z; R[tile][kk][7] = v1.w;
            short8 hi8, lo8;
            #pragma unroll
            for (int j = 0; j < 8; ++j) {
                short hi = f2bf(R[tile][kk][j]);
                hi8[j] = hi;
                lo8[j] = f2bf(R[tile][kk][j] - bf2f(hi));
            }
            Ahi[tile][kk] = hi8; Alo[tile][kk] = lo8;
        }

    float lossAcc[NSTAGE] = {0.f, 0.f, 0.f, 0.f};

    // prefetch stage 0 chunk 0 + stage 0 cn
    #pragma unroll
    for (int j = 0; j < 8; ++j) {
        int idx = t + j * 256;
        gload_lds16(fragAll + idx, &Bbuf[0][idx]);
    }
    #pragma unroll
    for (int j = 0; j < 2; ++j) {
        int idx = t + j * 256;                       // 16B units
        gload_lds16(ws + WS_CN + 4 * idx, &sCn[4 * idx]);
    }

    #pragma unroll 1
    for (int s = 0; s < NSTAGE; ++s) {
        const short8* frag = fragAll + (size_t)s * FRAG_S8;
        const float*  cbs  = cb + (size_t)s * KCB * DDIM;

        float d1[2][4], d2[2][4]; int i1[2][4], i2[2][4];
        #pragma unroll
        for (int tile = 0; tile < 2; ++tile)
            #pragma unroll
            for (int r = 0; r < 4; ++r) {
                d1[tile][r] = 3e38f; d2[tile][r] = 3e38f;
                i1[tile][r] = 0;     i2[tile][r] = 1;
            }

        #pragma unroll 1
        for (int c = 0; c < 32; ++c) {
            __syncthreads();                 // buf[c&1] + sCn resident
            if (c + 1 < 32) {
                const short8* src = frag + (size_t)(c + 1) * 2048;
                #pragma unroll
                for (int j = 0; j < 8; ++j) {
                    int idx = t + j * 256;
                    gload_lds16(src + idx, &Bbuf[(c + 1) & 1][idx]);
                }
            } else if (s + 1 < NSTAGE) {     // cross-stage prefetch into buf0
                const short8* src = frag + FRAG_S8;
                #pragma unroll
                for (int j = 0; j < 8; ++j) {
                    int idx = t + j * 256;
                    gload_lds16(src + idx, &Bbuf[0][idx]);
                }
            }
            const short8* B = Bbuf[c & 1];
            #pragma unroll
            for (int ng = 0; ng < 4; ++ng) {
                f32x4 a0 = {0.f, 0.f, 0.f, 0.f};     // tile0 x 16 cw
                f32x4 a1 = {0.f, 0.f, 0.f, 0.f};     // tile1 x 16 cw
                #pragma unroll
                for (int kk = 0; kk < 4; ++kk) {
                    short8 bh = B[((ng * 4 + kk) * 2 + 0) * 64 + lane];
                    short8 bl = B[((ng * 4 + kk) * 2 + 1) * 64 + lane];
                    a0 = __builtin_amdgcn_mfma_f32_16x16x32_bf16(Ahi[0][kk], bh, a0, 0, 0, 0);
                    a1 = __builtin_amdgcn_mfma_f32_16x16x32_bf16(Ahi[1][kk], bh, a1, 0, 0, 0);
                    a0 = __builtin_amdgcn_mfma_f32_16x16x32_bf16(Alo[0][kk], bh, a0, 0, 0, 0);
                    a1 = __builtin_amdgcn_mfma_f32_16x16x32_bf16(Alo[1][kk], bh, a1, 0, 0, 0);
                    a0 = __builtin_amdgcn_mfma_f32_16x16x32_bf16(Ahi[0][kk], bl, a0, 0, 0, 0);
                    a1 = __builtin_amdgcn_mfma_f32_16x16x32_bf16(Ahi[1][kk], bl, a1, 0, 0, 0);
                }
                // D layout: col = lane&15 (codeword), row(point) = q*4 + reg
                int   cw  = c * 64 + ng * 16 + m;
                float cnv = sCn[cw];
                #pragma unroll
                for (int r = 0; r < 4; ++r) {
                    float dt0 = fmaf(-2.f, a0[r], cnv);
                    upd2(d1[0][r], i1[0][r], d2[0][r], i2[0][r], dt0, cw);
                    float dt1 = fmaf(-2.f, a1[r], cnv);
                    upd2(d1[1][r], i1[1][r], d2[1][r], i2[1][r], dt1, cw);
                }
            }
        }

        // merge top-2 across the 16 codeword columns (m lanes)
        #pragma unroll
        for (int mm = 1; mm < 16; mm <<= 1) {
            #pragma unroll
            for (int tile = 0; tile < 2; ++tile)
                #pragma unroll
                for (int r = 0; r < 4; ++r) {
                    float od1 = __shfl_xor(d1[tile][r], mm); int oi1 = __shfl_xor(i1[tile][r], mm);
                    float od2 = __shfl_xor(d2[tile][r], mm); int oi2 = __shfl_xor(i2[tile][r], mm);
                    upd2(d1[tile][r], i1[tile][r], d2[tile][r], i2[tile][r], od1, oi1);
                    upd2(d1[tile][r], i1[tile][r], d2[tile][r], i2[tile][r], od2, oi2);
                }
        }
        if (m == 0) {                        // redistribute: D rows -> A rows
            #pragma unroll
            for (int tile = 0; tile < 2; ++tile)
                #pragma unroll
                for (int r = 0; r < 4; ++r)
                    { sC1[w * 32 + tile * 16 + q * 4 + r] = i1[tile][r];
                      sC2[w * 32 + tile * 16 + q * 4 + r] = i2[tile][r]; }
        }
        __syncthreads();

        #pragma unroll
        for (int tile = 0; tile < 2; ++tile) {
            int ia = sC1[w * 32 + tile * 16 + m];
            int ib = sC2[w * 32 + tile * 16 + m];

            // exact fp32 recheck against R: lane covers k = kk*32 + q*8 .. +8
            float pa = 0.f, pb = 0.f, pr = 0.f;
            #pragma unroll
            for (int kk = 0; kk < 4; ++kk) {
                const float* pav = cbs + (size_t)ia * DDIM + kk * 32 + q * 8;
                const float* pbv = cbs + (size_t)ib * DDIM + kk * 32 + q * 8;
                float4 a0 = *(const float4*)pav, a1 = *(const float4*)(pav + 4);
                float4 b0 = *(const float4*)pbv, b1 = *(const float4*)(pbv + 4);
                float av[8] = {a0.x, a0.y, a0.z, a0.w, a1.x, a1.y, a1.z, a1.w};
                float bv[8] = {b0.x, b0.y, b0.z, b0.w, b1.x, b1.y, b1.z, b1.w};
                #pragma unroll
                for (int j = 0; j < 8; ++j) {
                    float rv = R[tile][kk][j];
                    pa += rv * av[j];
                    pb += rv * bv[j];
                    pr += rv * rv;
                }
            }
            pa += __shfl_xor(pa, 16); pa += __shfl_xor(pa, 32);
            pb += __shfl_xor(pb, 16); pb += __shfl_xor(pb, 32);
            pr += __shfl_xor(pr, 16); pr += __shfl_xor(pr, 32);
            float dA = sCn[ia] - 2.f * pa;
            float dB = sCn[ib] - 2.f * pb;
            bool bw = (dB < dA) || (dB == dA && ib < ia);   // first-occurrence
            int  wi = bw ? ib : ia;
            if (q == 0) {
                out[IDX_OFF + pt[tile] * NSTAGE + s] = (float)wi;
                lossAcc[s] += (bw ? dB : dA) + pr;          // ||c - r||^2
            }

            // exact update: R -= c_win; re-split frags; last stage: x_q = x - R
            const float* cwr = cbs + (size_t)wi * DDIM;
            #pragma unroll
            for (int kk = 0; kk < 4; ++kk) {
                const float* pwv = cwr + kk * 32 + q * 8;
                float4 w0 = *(const float4*)pwv, w1 = *(const float4*)(pwv + 4);
                float wv[8] = {w0.x, w0.y, w0.z, w0.w, w1.x, w1.y, w1.z, w1.w};
                short8 hi8, lo8;
                #pragma unroll
                for (int j = 0; j < 8; ++j) {
                    float v = R[tile][kk][j] - wv[j];
                    R[tile][kk][j] = v;
                    short hi = f2bf(v);
                    hi8[j] = hi;
                    lo8[j] = f2bf(v - bf2f(hi));
                }
                Ahi[tile][kk] = hi8; Alo[tile][kk] = lo8;
                if (s == NSTAGE - 1) {
                    const float* xp = x + pt[tile] * DDIM + kk * 32 + q * 8;
                    float4 x0 = *(const float4*)xp, x1 = *(const float4*)(xp + 4);
                    float* op = out + pt[tile] * DDIM + kk * 32 + q * 8;
                    *(float4*)op = make_float4(x0.x - R[tile][kk][0], x0.y - R[tile][kk][1],
                                               x0.z - R[tile][kk][2], x0.w - R[tile][kk][3]);
                    *(float4*)(op + 4) = make_float4(x1.x - R[tile][kk][4], x1.y - R[tile][kk][5],
                                                     x1.z - R[tile][kk][6], x1.w - R[tile][kk][7]);
                }
            }
        }

        // stage-end barrier: recheck reads of sCn/sC done before next-stage
        // sCn overwrite and Bbuf reuse
        __syncthreads();
        if (s + 1 < NSTAGE) {                // stage s+1 cn -> LDS
            const float* cnn = ws + WS_CN + (s + 1) * KCB;
            #pragma unroll
            for (int j = 0; j < 2; ++j) {
                int idx = t + j * 256;
                gload_lds16(cnn + 4 * idx, &sCn[4 * idx]);
            }
        }
    }

    // loss: wave reduce, one atomic per wave per stage
    #pragma unroll
    for (int mm = 1; mm < 64; mm <<= 1)
        #pragma unroll
        for (int s2 = 0; s2 < NSTAGE; ++s2)
            lossAcc[s2] += __shfl_xor(lossAcc[s2], mm);
    if (lane == 0)
        #pragma unroll
        for (int s2 = 0; s2 < NSTAGE; ++s2)
            atomicAdd(ws + WS_LOSS + s2, lossAcc[s2]);
}

__global__ void rvq_finalize(const float* __restrict__ ws, float* __restrict__ out) {
    float sum = ws[0] + ws[1] + ws[2] + ws[3];
    out[XQ_SIZE] = (1.f + BETA_F) * sum /
                   ((float)NSTAGE * (float)N_PTS * (float)DDIM);
}

extern "C" void kernel_launch(void* const* d_in, const int* in_sizes, int n_in,
                              void* d_out, int out_size, void* d_ws, size_t ws_size,
                              hipStream_t stream) {
    const float* x  = (const float*)d_in[0];
    const float* cb = (const float*)d_in[1];
    float* out = (float*)d_out;
    float* ws  = (float*)d_ws;

    cnorm_init<<<512, 256, 0, stream>>>(cb, ws);
    frag_pack<<<1024, 256, 0, stream>>>(cb, ws);
    rvq_fused<<<512, 256, 0, stream>>>(x, cb, ws, out);
    rvq_finalize<<<1, 1, 0, stream>>>(ws, out);
}

// Round 8
// 609.000 us; speedup vs baseline: 5.8216x; 1.0752x over previous
//
#include <hip/hip_runtime.h>

// Residual VQ, fully fused, exact-fp32 residual chain, 2x M-blocked MFMA.
// Round 8: round-6 bitwise-identical approx math (single 12-MFMA chain per
// tile per ng — NEVER reorder: approx-distance bits are part of the passing
// contract) + deferred fold via ping-pong pending-acc sets (X/Y). The fold
// of ng runs while ng+1's chain flies, and distinct registers kill the WAR
// hazard that serialized MFMA->fold->MFMA in round 6.
// N=65536 pts, D=128, S=4 stages, K=2048 codewords.
// Out (flat f32): x_q [N*D] @0, mean_loss @N*D, indices [N,S] as float @N*D+1.

#define N_PTS   65536
#define DDIM    128
#define NSTAGE  4
#define KCB     2048
#define BETA_F  0.25f

#define XQ_SIZE (N_PTS * DDIM)
#define IDX_OFF (XQ_SIZE + 1)

// ws layout (float units)
#define WS_LOSS 0                         // 4 floats
#define WS_CN   16                        // NSTAGE*KCB floats
#define WS_FRAG (16 + NSTAGE * KCB)       // frag stream, 16B-aligned
#define FRAG_S8 (32 * 32 * 64)            // short8 per stage = 65536 (1 MB)

typedef __attribute__((ext_vector_type(8))) short short8;
typedef __attribute__((ext_vector_type(4))) float f32x4;

__device__ inline short f2bf(float x) {            // RTNE bf16
    union { float f; unsigned u; } v; v.f = x;
    unsigned r = v.u + 0x7FFFu + ((v.u >> 16) & 1u);
    return (short)(r >> 16);
}
__device__ inline float bf2f(short h) {
    union { unsigned u; float f; } v; v.u = ((unsigned)(unsigned short)h) << 16;
    return v.f;
}
__device__ inline void gload_lds16(const void* g, void* l) {
    __builtin_amdgcn_global_load_lds(
        (const __attribute__((address_space(1))) unsigned int*)g,
        (__attribute__((address_space(3))) unsigned int*)l, 16, 0, 0);
}
__device__ inline void upd2(float& d1, int& i1, float& d2, int& i2, float d, int i) {
    bool lt1 = d < d1;
    bool lt2 = d < d2;
    float nd2 = lt1 ? d1 : (lt2 ? d : d2);
    int   ni2 = lt1 ? i1 : (lt2 ? i : i2);
    d1 = lt1 ? d : d1;  i1 = lt1 ? i : i1;
    d2 = nd2;           i2 = ni2;
}

// ||c||^2 per codeword + zero loss accumulators
__global__ void cnorm_init(const float* __restrict__ cb, float* __restrict__ ws) {
    int t = blockIdx.x * blockDim.x + threadIdx.x;   // 131072 threads
    int row = t >> 4;                                // 0..8191 (s*K + k)
    int q   = t & 15;
    const float4* rp = (const float4*)(cb + (size_t)row * DDIM);
    float s = 0.f;
    #pragma unroll
    for (int j = 0; j < 2; ++j) {
        float4 v = rp[q * 2 + j];
        s += v.x * v.x + v.y * v.y + v.z * v.z + v.w * v.w;
    }
    #pragma unroll
    for (int m = 1; m < 16; m <<= 1) s += __shfl_xor(s, m);
    if (q == 0) ws[WS_CN + row] = s;
    if (t < 4) ws[WS_LOSS + t] = 0.f;
}

// Pack codebook into MFMA-B-frag-linear bf16 hi/lo layout:
// id = (((s*32 + c)*4 + nt)*4 + kk)*2*64 + h*64 + lane ; 16 B per id.
// lane's 8 bf16 = cb[s][c*64 + nt*16 + (lane&15)][kk*32 + (lane>>4)*8 .. +8]
__global__ void frag_pack(const float* __restrict__ cb, float* __restrict__ ws) {
    int id   = blockIdx.x * 256 + threadIdx.x;       // 0..262143
    int lane = id & 63;
    int h    = (id >> 6) & 1;
    int kk   = (id >> 7) & 3;
    int nt   = (id >> 9) & 3;
    int c    = (id >> 11) & 31;
    int s    = (id >> 16);
    int row  = c * 64 + nt * 16 + (lane & 15);
    int koff = kk * 32 + (lane >> 4) * 8;
    const float* src = cb + ((size_t)(s * KCB + row) * DDIM + koff);
    short8 v;
    #pragma unroll
    for (int j = 0; j < 8; ++j) {
        float xv = src[j];
        short hi = f2bf(xv);
        if (h) { v[j] = f2bf(xv - bf2f(hi)); }
        else   { v[j] = hi; }
    }
    ((short8*)(ws + WS_FRAG))[id] = v;
}

#define MFMA16(A, B, C) __builtin_amdgcn_mfma_f32_16x16x32_bf16(A, B, C, 0, 0, 0)

__global__ __launch_bounds__(256, 2)
void rvq_fused(const float* __restrict__ x, const float* __restrict__ cb,
               float* __restrict__ ws, float* __restrict__ out) {
    __shared__ short8 Bbuf[2][2048];                 // 2 x 32 KB
    __shared__ float  sCn[KCB];                      // 8 KB, per-stage ||c||^2
    __shared__ int    sC1[128], sC2[128];

    const int t    = threadIdx.x;
    const int lane = t & 63;
    const int w    = t >> 6;                         // wave 0..3
    const int m    = lane & 15;
    const int q    = lane >> 4;
    const size_t pbase = (size_t)blockIdx.x * 128 + w * 32;  // wave's 32 points
    const size_t pt[2] = {pbase + m, pbase + 16 + m};

    const short8* fragAll = (const short8*)(ws + WS_FRAG);

    // Exact fp32 residual R + split-bf16 A-frags, 2 M-tiles.
    // A[tile][m][k]: row m = point pt[tile], k = kk*32 + q*8 + j.
    float  R[2][4][8];
    short8 Ahi[2][4], Alo[2][4];
    #pragma unroll
    for (int tile = 0; tile < 2; ++tile)
        #pragma unroll
        for (int kk = 0; kk < 4; ++kk) {
            const float* rp = x + pt[tile] * DDIM + kk * 32 + q * 8;
            float4 v0 = *(const float4*)rp;
            float4 v1 = *(const float4*)(rp + 4);
            R[tile][kk][0] = v0.x; R[tile][kk][1] = v0.y;
            R[tile][kk][2] = v0.z; R[tile][kk][3] = v0.w;
            R[tile][kk][4] = v1.x; R[tile][kk][5] = v1.y;
            R[tile][kk][6] = v1.z; R[tile][kk][7] = v1.w;
            short8 hi8, lo8;
            #pragma unroll
            for (int j = 0; j < 8; ++j) {
                short hi = f2bf(R[tile][kk][j]);
                hi8[j] = hi;
                lo8[j] = f2bf(R[tile][kk][j] - bf2f(hi));
            }
            Ahi[tile][kk] = hi8; Alo[tile][kk] = lo8;
        }

    float lossAcc[NSTAGE] = {0.f, 0.f, 0.f, 0.f};

    // prefetch stage 0 chunk 0 + stage 0 cn
    #pragma unroll
    for (int j = 0; j < 8; ++j) {
        int idx = t + j * 256;
        gload_lds16(fragAll + idx, &Bbuf[0][idx]);
    }
    #pragma unroll
    for (int j = 0; j < 2; ++j) {
        int idx = t + j * 256;                       // 16B units
        gload_lds16(ws + WS_CN + 4 * idx, &sCn[4 * idx]);
    }

    #pragma unroll 1
    for (int s = 0; s < NSTAGE; ++s) {
        const short8* frag = fragAll + (size_t)s * FRAG_S8;
        const float*  cbs  = cb + (size_t)s * KCB * DDIM;

        float d1[2][4], d2[2][4]; int i1[2][4], i2[2][4];
        #pragma unroll
        for (int tile = 0; tile < 2; ++tile)
            #pragma unroll
            for (int r = 0; r < 4; ++r) {
                d1[tile][r] = 3e38f; d2[tile][r] = 3e38f;
                i1[tile][r] = 0;     i2[tile][r] = 1;
            }

        // Deferred-fold pending acc sets (distinct registers -> no WAR with
        // the next chain). Y starts fake: dist = +1.2e38, evicted by the
        // first two real candidates; cwp=0. Fold values are bitwise-identical
        // to round 6 (same chain, same fmaf, same ascending cw order).
        const f32x4 fake = {-3e37f, -3e37f, -3e37f, -3e37f};
        f32x4 Xa0 = fake, Xa1 = fake, Ya0 = fake, Ya1 = fake;
        int cwp = 0;

        #pragma unroll 1
        for (int c = 0; c < 32; ++c) {
            __syncthreads();                 // buf[c&1] + sCn resident
            if (c + 1 < 32) {
                const short8* src = frag + (size_t)(c + 1) * 2048;
                #pragma unroll
                for (int j = 0; j < 8; ++j) {
                    int idx = t + j * 256;
                    gload_lds16(src + idx, &Bbuf[(c + 1) & 1][idx]);
                }
            } else if (s + 1 < NSTAGE) {     // cross-stage prefetch into buf0
                const short8* src = frag + FRAG_S8;
                #pragma unroll
                for (int j = 0; j < 8; ++j) {
                    int idx = t + j * 256;
                    gload_lds16(src + idx, &Bbuf[0][idx]);
                }
            }
            const short8* B = Bbuf[c & 1];
            #pragma unroll
            for (int ng = 0; ng < 4; ++ng) {
                // ---- fold pending (deferred one ng; other parity set)
                {
                    float cnv = sCn[cwp];
                    if ((ng & 1) == 0) {
                        #pragma unroll
                        for (int r = 0; r < 4; ++r) {
                            float dt0 = fmaf(-2.f, Ya0[r], cnv);
                            upd2(d1[0][r], i1[0][r], d2[0][r], i2[0][r], dt0, cwp);
                            float dt1 = fmaf(-2.f, Ya1[r], cnv);
                            upd2(d1[1][r], i1[1][r], d2[1][r], i2[1][r], dt1, cwp);
                        }
                    } else {
                        #pragma unroll
                        for (int r = 0; r < 4; ++r) {
                            float dt0 = fmaf(-2.f, Xa0[r], cnv);
                            upd2(d1[0][r], i1[0][r], d2[0][r], i2[0][r], dt0, cwp);
                            float dt1 = fmaf(-2.f, Xa1[r], cnv);
                            upd2(d1[1][r], i1[1][r], d2[1][r], i2[1][r], dt1, cwp);
                        }
                    }
                }
                // ---- chain ng: round-6 bitwise order (single chain per tile)
                f32x4 ca0 = {0.f, 0.f, 0.f, 0.f};
                f32x4 ca1 = {0.f, 0.f, 0.f, 0.f};
                #pragma unroll
                for (int kk = 0; kk < 4; ++kk) {
                    short8 bh = B[((ng * 4 + kk) * 2 + 0) * 64 + lane];
                    short8 bl = B[((ng * 4 + kk) * 2 + 1) * 64 + lane];
                    ca0 = MFMA16(Ahi[0][kk], bh, ca0);
                    ca1 = MFMA16(Ahi[1][kk], bh, ca1);
                    ca0 = MFMA16(Alo[0][kk], bh, ca0);
                    ca1 = MFMA16(Alo[1][kk], bh, ca1);
                    ca0 = MFMA16(Ahi[0][kk], bl, ca0);
                    ca1 = MFMA16(Ahi[1][kk], bl, ca1);
                }
                // ---- stash as pending
                if ((ng & 1) == 0) { Xa0 = ca0; Xa1 = ca1; }
                else               { Ya0 = ca0; Ya1 = ca1; }
                cwp = c * 64 + ng * 16 + m;
            }
        }
        // final pending fold (set Y, from c=31 ng=3)
        {
            float cnv = sCn[cwp];
            #pragma unroll
            for (int r = 0; r < 4; ++r) {
                float dt0 = fmaf(-2.f, Ya0[r], cnv);
                upd2(d1[0][r], i1[0][r], d2[0][r], i2[0][r], dt0, cwp);
                float dt1 = fmaf(-2.f, Ya1[r], cnv);
                upd2(d1[1][r], i1[1][r], d2[1][r], i2[1][r], dt1, cwp);
            }
        }

        // merge top-2 across the 16 codeword columns (m lanes)
        #pragma unroll
        for (int mm = 1; mm < 16; mm <<= 1) {
            #pragma unroll
            for (int tile = 0; tile < 2; ++tile)
                #pragma unroll
                for (int r = 0; r < 4; ++r) {
                    float od1 = __shfl_xor(d1[tile][r], mm); int oi1 = __shfl_xor(i1[tile][r], mm);
                    float od2 = __shfl_xor(d2[tile][r], mm); int oi2 = __shfl_xor(i2[tile][r], mm);
                    upd2(d1[tile][r], i1[tile][r], d2[tile][r], i2[tile][r], od1, oi1);
                    upd2(d1[tile][r], i1[tile][r], d2[tile][r], i2[tile][r], od2, oi2);
                }
        }
        if (m == 0) {                        // redistribute: D rows -> A rows
            #pragma unroll
            for (int tile = 0; tile < 2; ++tile)
                #pragma unroll
                for (int r = 0; r < 4; ++r)
                    { sC1[w * 32 + tile * 16 + q * 4 + r] = i1[tile][r];
                      sC2[w * 32 + tile * 16 + q * 4 + r] = i2[tile][r]; }
        }
        __syncthreads();

        #pragma unroll
        for (int tile = 0; tile < 2; ++tile) {
            int ia = sC1[w * 32 + tile * 16 + m];
            int ib = sC2[w * 32 + tile * 16 + m];

            // exact fp32 recheck against R: lane covers k = kk*32 + q*8 .. +8
            float pa = 0.f, pb = 0.f, pr = 0.f;
            #pragma unroll
            for (int kk = 0; kk < 4; ++kk) {
                const float* pav = cbs + (size_t)ia * DDIM + kk * 32 + q * 8;
                const float* pbv = cbs + (size_t)ib * DDIM + kk * 32 + q * 8;
                float4 a0 = *(const float4*)pav, a1 = *(const float4*)(pav + 4);
                float4 b0 = *(const float4*)pbv, b1 = *(const float4*)(pbv + 4);
                float av[8] = {a0.x, a0.y, a0.z, a0.w, a1.x, a1.y, a1.z, a1.w};
                float bv[8] = {b0.x, b0.y, b0.z, b0.w, b1.x, b1.y, b1.z, b1.w};
                #pragma unroll
                for (int j = 0; j < 8; ++j) {
                    float rv = R[tile][kk][j];
                    pa += rv * av[j];
                    pb += rv * bv[j];
                    pr += rv * rv;
                }
            }
            pa += __shfl_xor(pa, 16); pa += __shfl_xor(pa, 32);
            pb += __shfl_xor(pb, 16); pb += __shfl_xor(pb, 32);
            pr += __shfl_xor(pr, 16); pr += __shfl_xor(pr, 32);
            float dA = sCn[ia] - 2.f * pa;
            float dB = sCn[ib] - 2.f * pb;
            bool bw = (dB < dA) || (dB == dA && ib < ia);   // first-occurrence
            int  wi = bw ? ib : ia;
            if (q == 0) {
                out[IDX_OFF + pt[tile] * NSTAGE + s] = (float)wi;
                lossAcc[s] += (bw ? dB : dA) + pr;          // ||c - r||^2
            }

            // exact update: R -= c_win; re-split frags; last stage: x_q = x - R
            const float* cwr = cbs + (size_t)wi * DDIM;
            #pragma unroll
            for (int kk = 0; kk < 4; ++kk) {
                const float* pwv = cwr + kk * 32 + q * 8;
                float4 w0 = *(const float4*)pwv, w1 = *(const float4*)(pwv + 4);
                float wv[8] = {w0.x, w0.y, w0.z, w0.w, w1.x, w1.y, w1.z, w1.w};
                short8 hi8, lo8;
                #pragma unroll
                for (int j = 0; j < 8; ++j) {
                    float v = R[tile][kk][j] - wv[j];
                    R[tile][kk][j] = v;
                    short hi = f2bf(v);
                    hi8[j] = hi;
                    lo8[j] = f2bf(v - bf2f(hi));
                }
                Ahi[tile][kk] = hi8; Alo[tile][kk] = lo8;
                if (s == NSTAGE - 1) {
                    const float* xp = x + pt[tile] * DDIM + kk * 32 + q * 8;
                    float4 x0 = *(const float4*)xp, x1 = *(const float4*)(xp + 4);
                    float* op = out + pt[tile] * DDIM + kk * 32 + q * 8;
                    *(float4*)op = make_float4(x0.x - R[tile][kk][0], x0.y - R[tile][kk][1],
                                               x0.z - R[tile][kk][2], x0.w - R[tile][kk][3]);
                    *(float4*)(op + 4) = make_float4(x1.x - R[tile][kk][4], x1.y - R[tile][kk][5],
                                                     x1.z - R[tile][kk][6], x1.w - R[tile][kk][7]);
                }
            }
        }

        // stage-end barrier: recheck reads of sCn/sC done before next-stage
        // sCn overwrite and Bbuf reuse
        __syncthreads();
        if (s + 1 < NSTAGE) {                // stage s+1 cn -> LDS
            const float* cnn = ws + WS_CN + (s + 1) * KCB;
            #pragma unroll
            for (int j = 0; j < 2; ++j) {
                int idx = t + j * 256;
                gload_lds16(cnn + 4 * idx, &sCn[4 * idx]);
            }
        }
    }

    // loss: wave reduce, one atomic per wave per stage
    #pragma unroll
    for (int mm = 1; mm < 64; mm <<= 1)
        #pragma unroll
        for (int s2 = 0; s2 < NSTAGE; ++s2)
            lossAcc[s2] += __shfl_xor(lossAcc[s2], mm);
    if (lane == 0)
        #pragma unroll
        for (int s2 = 0; s2 < NSTAGE; ++s2)
            atomicAdd(ws + WS_LOSS + s2, lossAcc[s2]);
}

__global__ void rvq_finalize(const float* __restrict__ ws, float* __restrict__ out) {
    float sum = ws[0] + ws[1] + ws[2] + ws[3];
    out[XQ_SIZE] = (1.f + BETA_F) * sum /
                   ((float)NSTAGE * (float)N_PTS * (float)DDIM);
}

extern "C" void kernel_launch(void* const* d_in, const int* in_sizes, int n_in,
                              void* d_out, int out_size, void* d_ws, size_t ws_size,
                              hipStream_t stream) {
    const float* x  = (const float*)d_in[0];
    const float* cb = (const float*)d_in[1];
    float* out = (float*)d_out;
    float* ws  = (float*)d_ws;

    cnorm_init<<<512, 256, 0, stream>>>(cb, ws);
    frag_pack<<<1024, 256, 0, stream>>>(cb, ws);
    rvq_fused<<<512, 256, 0, stream>>>(x, cb, ws, out);
    rvq_finalize<<<1, 1, 0, stream>>>(ws, out);
}